// Round 10
// baseline (373.270 us; speedup 1.0000x reference)
//
#include <hip/hip_runtime.h>
#include <hip/hip_bf16.h>
#include <cstdint>

// ---------- types ----------
typedef __attribute__((ext_vector_type(8))) short short8;     // 8 x bf16 raw
typedef __attribute__((ext_vector_type(4))) short short4v;    // 4 x bf16 raw
typedef __attribute__((ext_vector_type(4))) float floatx4;
typedef __attribute__((ext_vector_type(4))) unsigned short ushort4v;
typedef __attribute__((ext_vector_type(4))) unsigned int uint4v;

// ---------- helpers ----------
__device__ __forceinline__ float bf2f(unsigned short u) {
    union { unsigned int u; float f; } v;
    v.u = ((unsigned int)u) << 16;
    return v.f;
}
__device__ __forceinline__ unsigned short f2bf(float f) {
    union { float f; unsigned int u; } v; v.f = f;
    unsigned int u = v.u;
    unsigned int r = (u + 0x7FFFu + ((u >> 16) & 1u)) >> 16;  // RNE
    return (unsigned short)r;
}
__device__ __forceinline__ float lo_bf(unsigned int u) {
    union { unsigned int u; float f; } v; v.u = u << 16; return v.f;
}
__device__ __forceinline__ float hi_bf(unsigned int u) {
    union { unsigned int u; float f; } v; v.u = u & 0xffff0000u; return v.f;
}
__device__ __forceinline__ void gld_lds16(const void* g, void* l) {
    __builtin_amdgcn_global_load_lds(
        (const __attribute__((address_space(1))) unsigned int*)g,
        (__attribute__((address_space(3))) unsigned int*)l,
        16, 0, 0);
}
// pack 2 f32 -> 2 bf16 in one u32 (lo = first arg)
__device__ __forceinline__ unsigned int cvtpk_bf16(float lo, float hi) {
    unsigned int r;
    asm("v_cvt_pk_bf16_f32 %0, %1, %2" : "=v"(r) : "v"(lo), "v"(hi));
    return r;
}

// ---------- prep: weight transposes ONLY (feature cvt fused into gemm_f12) ----------
// blocks [0,1024)    : transpose W1   [2048][1024] (32x32 tiles)
// blocks [1024,1408) : transpose W2   [768][1024]  (12x32)
// blocks [1408,2944) : transpose Wqkv [1024][3072] (16x96)
// blocks [2944,3456) : transpose Wout [1024][1024] (16x32)
__global__ __launch_bounds__(256) void prep_kernel(
    const float* __restrict__ W1, unsigned short* __restrict__ W1t,
    const float* __restrict__ W2, unsigned short* __restrict__ W2t,
    const float* __restrict__ Wqkv, unsigned short* __restrict__ Wqkvt,
    const float* __restrict__ Wout, unsigned short* __restrict__ Woutt) {
    __shared__ float tile[64][33];
    const int b = blockIdx.x;
    const int tid = threadIdx.x;

    const float* in; unsigned short* outp; int K, N, t;
    if (b < 1024)      { in = W1;   outp = W1t;   K = 2048; N = 1024; t = b; }
    else if (b < 1408) { in = W2;   outp = W2t;   K = 768;  N = 1024; t = b - 1024; }
    else if (b < 2944) { in = Wqkv; outp = Wqkvt; K = 1024; N = 3072; t = b - 1408; }
    else               { in = Wout; outp = Woutt; K = 1024; N = 1024; t = b - 2944; }
    const int ntiles = N >> 5;
    const int n0 = (t % ntiles) * 32;
    const int k0 = (t / ntiles) * 64;
    const int tx = tid & 31, tg = tid >> 5;
#pragma unroll
    for (int i = 0; i < 8; i++)
        tile[tg * 8 + i][tx] = in[(size_t)(k0 + tg * 8 + i) * N + n0 + tx];
    __syncthreads();
    const int n = tid >> 3, kc = (tid & 7) * 8;
    short8 o;
#pragma unroll
    for (int j = 0; j < 8; j++) o[j] = (short)f2bf(tile[kc + j][n]);
    *(short8*)&outp[(size_t)(n0 + n) * K + k0 + kc] = o;
}

// ---------- bf16 GEMM core, BK=64 (r1-verified: swizzled LDS, 2-phase) ----------
template <bool OUT_BF16, bool HAS_BIAS>
__device__ __forceinline__ void gemm_core(const unsigned short* __restrict__ A,
                                          const unsigned short* __restrict__ Bt,
                                          void* __restrict__ Cv, const float* __restrict__ bias,
                                          int K, int ldc, int blockM, int blockN,
                                          unsigned short* As, unsigned short* Bs) {
    const int tid  = threadIdx.x;
    const int lane = tid & 63;
    const int wave = tid >> 6;
    const int wm = wave >> 1, wn = wave & 1;

    const int kx = (tid >> 3) & 3;
    const unsigned short* gA = A  + (size_t)(blockM + (tid >> 2)) * K + ((tid & 3) ^ kx) * 8;
    const unsigned short* gB = Bt + (size_t)(blockN + (tid >> 2)) * K + ((tid & 3) ^ kx) * 8;
    const size_t sK = (size_t)64 * K;
    unsigned short* lA = As + wave * 512;
    unsigned short* lB = Bs + wave * 512;

    floatx4 acc[4][4];
#pragma unroll
    for (int i = 0; i < 4; i++)
#pragma unroll
        for (int j = 0; j < 4; j++) acc[i][j] = (floatx4){0.f, 0.f, 0.f, 0.f};

    const int col  = lane & 15;
    const int quad = lane >> 4;
    const int qx = quad ^ ((col >> 1) & 3);
    const int aoff32 = (wm * 64 + col) * 32 + qx * 8;
    const int boff32 = (wn * 64 + col) * 32 + qx * 8;

    const int kIters = K >> 6;
    for (int kt = 0; kt < kIters; ++kt) {
        const size_t ko = (size_t)kt * 64;
        gld_lds16(gA + ko,           lA);
        gld_lds16(gA + sK + ko,      lA + 2048);
        gld_lds16(gA + 32 + ko,      lA + 4096);
        gld_lds16(gA + sK + 32 + ko, lA + 6144);
        gld_lds16(gB + ko,           lB);
        gld_lds16(gB + sK + ko,      lB + 2048);
        gld_lds16(gB + 32 + ko,      lB + 4096);
        gld_lds16(gB + sK + 32 + ko, lB + 6144);
        __syncthreads();

#pragma unroll
        for (int hh = 0; hh < 2; hh++) {
            short8 a[4];
#pragma unroll
            for (int i = 0; i < 4; i++) a[i] = *(const short8*)&As[hh * 4096 + aoff32 + i * 512];
#pragma unroll
            for (int j = 0; j < 4; j++) {
                short8 bj = *(const short8*)&Bs[hh * 4096 + boff32 + j * 512];
#pragma unroll
                for (int i = 0; i < 4; i++)
                    acc[i][j] = __builtin_amdgcn_mfma_f32_16x16x32_bf16(a[i], bj, acc[i][j], 0, 0, 0);
            }
        }
        __syncthreads();
    }

#pragma unroll
    for (int i = 0; i < 4; i++) {
#pragma unroll
        for (int j = 0; j < 4; j++) {
#pragma unroll
            for (int r = 0; r < 4; r++) {
                int row = blockM + wm * 64 + i * 16 + quad * 4 + r;
                int cn  = blockN + wn * 64 + j * 16 + col;
                float v = acc[i][j][r];
                if (HAS_BIAS) v += bias[cn];
                if (OUT_BF16) ((unsigned short*)Cv)[(size_t)row * ldc + cn] = f2bf(v);
                else          ((float*)Cv)[(size_t)row * ldc + cn] = v;
            }
        }
    }
}

// ---------- modality GEMMs with FUSED f32->bf16 A-conversion ----------
// A (features) is read as f32 float4 pairs into REGISTERS (issued one tile early,
// before the post-read barrier: pure-register, no LDS hazard -> HBM latency hides
// under the MFMA phase), converted with v_cvt_pk_bf16_f32, and ds_write_b128'd into
// the byte-identical LDS layout gemm_core uses (same swizzle, same frag reads).
// B stays on the verified global_load_lds path. Compiler auto-inserts the counted
// vmcnt before the cvt reads (4 newer B-loads stay in flight). (256,3): +32 VGPR
// for in-flight f32 makes (256,4)'s 128-VGPR cap spill-risky; 3 vs 4 blocks/CU
// measured as noise for f12 (r7 vs r3).
__global__ __launch_bounds__(256, 3)
void gemm_f12(const float* __restrict__ f1, const unsigned short* __restrict__ W1t,
              const float* __restrict__ b1,
              const float* __restrict__ f2, const unsigned short* __restrict__ W2t,
              const float* __restrict__ b2, unsigned short* __restrict__ xb) {
    __shared__ alignas(16) unsigned short As[8192];
    __shared__ alignas(16) unsigned short Bs[8192];
    const int tid  = threadIdx.x;
    const int lane = tid & 63;
    const int wave = tid >> 6;
    const int wm = wave >> 1, wn = wave & 1;
    const int blockM = blockIdx.x * 128;
    const int blockN = blockIdx.y * 128;

    const float* A; const unsigned short* Bt; const float* bias; int K; unsigned short* Cp;
    if (blockIdx.z == 0) { A = f1; Bt = W1t; bias = b1; K = 2048; Cp = xb; }
    else                 { A = f2; Bt = W2t; bias = b2; K = 768;  Cp = xb + 1024; }

    const int kx = (tid >> 3) & 3;
    const int srow = tid >> 2;                       // 0..63
    const int sc8  = ((tid & 3) ^ kx) * 8;           // swizzled 8-elem chunk (r1 pattern)
    const float* gA = A + (size_t)(blockM + srow) * K + sc8;
    const unsigned short* gB = Bt + (size_t)(blockN + srow) * K + sc8;
    const size_t sK = (size_t)64 * K;
    unsigned short* lB = Bs + wave * 512;
    const int awbase = wave * 512 + lane * 8;        // A ds_write dest (elem) within slot

    floatx4 acc[4][4];
#pragma unroll
    for (int i = 0; i < 4; i++)
#pragma unroll
        for (int j = 0; j < 4; j++) acc[i][j] = (floatx4){0.f, 0.f, 0.f, 0.f};

    const int col  = lane & 15;
    const int quad = lane >> 4;
    const int qx = quad ^ ((col >> 1) & 3);
    const int aoff32 = (wm * 64 + col) * 32 + qx * 8;
    const int boff32 = (wn * 64 + col) * 32 + qx * 8;

    float4 af[4][2];   // in-flight f32 for 4 slots x 8 elems
#define ISSUE_A(ko) do { \
    af[0][0] = *(const float4*)(gA + (ko));           af[0][1] = *(const float4*)(gA + (ko) + 4); \
    af[1][0] = *(const float4*)(gA + sK + (ko));      af[1][1] = *(const float4*)(gA + sK + (ko) + 4); \
    af[2][0] = *(const float4*)(gA + 32 + (ko));      af[2][1] = *(const float4*)(gA + 32 + (ko) + 4); \
    af[3][0] = *(const float4*)(gA + sK + 32 + (ko)); af[3][1] = *(const float4*)(gA + sK + 32 + (ko) + 4); } while (0)

    const int kIters = K >> 6;
    ISSUE_A(0);
    for (int kt = 0; kt < kIters; ++kt) {
        const size_t ko = (size_t)kt * 64;
        // B staging (verified gload_lds path)
        gld_lds16(gB + ko,           lB);
        gld_lds16(gB + sK + ko,      lB + 2048);
        gld_lds16(gB + 32 + ko,      lB + 4096);
        gld_lds16(gB + sK + 32 + ko, lB + 6144);
        // A: cvt in-flight f32 (compiler emits vmcnt(4) here) + ds_write to identical layout
#pragma unroll
        for (int s = 0; s < 4; s++) {
            uint4v pk;
            pk.x = cvtpk_bf16(af[s][0].x, af[s][0].y);
            pk.y = cvtpk_bf16(af[s][0].z, af[s][0].w);
            pk.z = cvtpk_bf16(af[s][1].x, af[s][1].y);
            pk.w = cvtpk_bf16(af[s][1].z, af[s][1].w);
            *(uint4v*)&As[s * 2048 + awbase] = pk;
        }
        __syncthreads();   // drains B gload_lds + A ds_writes

#pragma unroll
        for (int hh = 0; hh < 2; hh++) {
            short8 a[4];
#pragma unroll
            for (int i = 0; i < 4; i++) a[i] = *(const short8*)&As[hh * 4096 + aoff32 + i * 512];
#pragma unroll
            for (int j = 0; j < 4; j++) {
                short8 bj = *(const short8*)&Bs[hh * 4096 + boff32 + j * 512];
#pragma unroll
                for (int i = 0; i < 4; i++)
                    acc[i][j] = __builtin_amdgcn_mfma_f32_16x16x32_bf16(a[i], bj, acc[i][j], 0, 0, 0);
            }
        }
        if (kt + 1 < kIters) ISSUE_A(ko + 64);   // early-issue next tile's A (registers only)
        __syncthreads();
    }
#undef ISSUE_A

#pragma unroll
    for (int i = 0; i < 4; i++) {
#pragma unroll
        for (int j = 0; j < 4; j++) {
#pragma unroll
            for (int r = 0; r < 4; r++) {
                int row = blockM + wm * 64 + i * 16 + quad * 4 + r;
                int cn  = blockN + wn * 64 + j * 16 + col;
                float v = acc[i][j][r] + bias[cn];
                Cp[(size_t)row * 2048 + cn] = f2bf(v);
            }
        }
    }
}

// ---------- out-proj GEMM (unchanged A/A guard) ----------
__global__ __launch_bounds__(256, 4)
void gemm_proj(const unsigned short* __restrict__ attn, const unsigned short* __restrict__ Woutt,
               const float* __restrict__ bout, unsigned short* __restrict__ projb) {
    __shared__ alignas(16) unsigned short As[8192];
    __shared__ alignas(16) unsigned short Bs[8192];
    gemm_core<true, true>(attn, Woutt, (void*)projb, bout, 1024, 1024,
                          blockIdx.x * 128, blockIdx.y * 128, As, Bs);
}

// ---------- fused qkv GEMM + 2x2 attention (r1 exact; best verified 100.5 us) ----------
#define T2_STRIDE 132
__global__ __launch_bounds__(256, 3)
void gemm_qkv_attn(const unsigned short* __restrict__ A, const unsigned short* __restrict__ Bt,
                   unsigned short* __restrict__ attn_out) {
    __shared__ alignas(16) char smem[52224];
    unsigned short* As = (unsigned short*)smem;        // 8192 elems: 2 halves x [128][32]
    unsigned short* Bs = As + 8192;                    // 12288 elems: 2 halves x [192][32]
    unsigned short* T2 = (unsigned short*)smem;        // 192*132 elems, reuses staging
    float* wsm = (float*)(smem + 50688);               // 64*4 softmax weights

    const int tid  = threadIdx.x;
    const int lane = tid & 63;
    const int wave = tid >> 6;
    const int g = blockIdx.x;
    const int h = g >> 7;                     // head 0..15
    const int blockM = (g & 127) * 128;       // M-tile fastest => same-XCD A sharing
    const int wm = wave >> 1, wn = wave & 1;  // wave tile 64x96
    const int K = 1024;

    const int kx = (tid >> 3) & 3;            // staging-side chunk XOR (verified r1)
    const unsigned short* gA = A  + (size_t)(blockM + (tid >> 2)) * K + ((tid & 3) ^ kx) * 8;
    const unsigned short* gB = Bt + (size_t)(h * 64 + (tid >> 2)) * K + ((tid & 3) ^ kx) * 8;
    unsigned short* lA = As + wave * 512;
    unsigned short* lB = Bs + wave * 512;

    floatx4 acc[4][6];
#pragma unroll
    for (int i = 0; i < 4; i++)
#pragma unroll
        for (int j = 0; j < 6; j++) acc[i][j] = (floatx4){0.f, 0.f, 0.f, 0.f};

    const int col  = lane & 15;
    const int quad = lane >> 4;
    const int qx = quad ^ ((col >> 1) & 3);   // read-side swizzled chunk (verified r1)
    const int aoff32 = (wm * 64 + col) * 32 + qx * 8;
    const int boff32 = (wn * 96 + col) * 32 + qx * 8;

    for (int kt = 0; kt < 16; ++kt) {
        const size_t ko = (size_t)kt * 64;
        gld_lds16(gA + ko,               lA);          // A half0 rows 0..63
        gld_lds16(gA + 65536 + ko,       lA + 2048);   // A half0 rows 64..127
        gld_lds16(gA + 32 + ko,          lA + 4096);   // A half1 rows 0..63
        gld_lds16(gA + 65536 + 32 + ko,  lA + 6144);   // A half1 rows 64..127
        gld_lds16(gB + ko,               lB);          // q, half0
        gld_lds16(gB + 1048576 + ko,     lB + 2048);   // k, half0
        gld_lds16(gB + 2097152 + ko,     lB + 4096);   // v, half0
        gld_lds16(gB + 32 + ko,          lB + 6144);   // q, half1
        gld_lds16(gB + 1048576 + 32 + ko, lB + 8192);  // k, half1
        gld_lds16(gB + 2097152 + 32 + ko, lB + 10240); // v, half1
        __syncthreads();

#pragma unroll
        for (int hh = 0; hh < 2; hh++) {
            short8 a[4];
#pragma unroll
            for (int i = 0; i < 4; i++) a[i] = *(const short8*)&As[hh * 4096 + aoff32 + i * 512];
#pragma unroll
            for (int j = 0; j < 6; j++) {
                short8 bj = *(const short8*)&Bs[hh * 6144 + boff32 + j * 512];
#pragma unroll
                for (int i = 0; i < 4; i++)
                    acc[i][j] = __builtin_amdgcn_mfma_f32_16x16x32_bf16(a[i], bj, acc[i][j], 0, 0, 0);
            }
        }
        __syncthreads();
    }

    // 1) store tile transposed: T2[c][r], c = feature (q|k|v), r = M-row
#pragma unroll
    for (int i = 0; i < 4; i++) {
#pragma unroll
        for (int j = 0; j < 6; j++) {
            int c  = wn * 96 + j * 16 + col;
            int r0 = wm * 64 + i * 16 + quad * 4;
            short4v pk;
            pk.x = (short)f2bf(acc[i][j][0]);
            pk.y = (short)f2bf(acc[i][j][1]);
            pk.z = (short)f2bf(acc[i][j][2]);
            pk.w = (short)f2bf(acc[i][j][3]);
            *(short4v*)&T2[c * T2_STRIDE + r0] = pk;
        }
    }
    __syncthreads();

    // 2) scores + softmax: thread ib (<64) handles batch-row pair (2ib, 2ib+1)
    if (tid < 64) {
        const int ib = tid;
        float s00 = 0.f, s01 = 0.f, s10 = 0.f, s11 = 0.f;
#pragma unroll 8
        for (int d = 0; d < 64; d++) {
            unsigned int qp = *(const unsigned int*)&T2[d * T2_STRIDE + 2 * ib];
            unsigned int kp = *(const unsigned int*)&T2[(64 + d) * T2_STRIDE + 2 * ib];
            float q0 = lo_bf(qp), q1 = hi_bf(qp);
            float k0 = lo_bf(kp), k1 = hi_bf(kp);
            s00 += q0 * k0; s01 += q0 * k1;
            s10 += q1 * k0; s11 += q1 * k1;
        }
        const float sc = 0.125f;   // (1024/16)^-0.5
        s00 *= sc; s01 *= sc; s10 *= sc; s11 *= sc;
        float m0 = fmaxf(s00, s01), m1 = fmaxf(s10, s11);
        float e00 = __expf(s00 - m0), e01 = __expf(s01 - m0);
        float e10 = __expf(s10 - m1), e11 = __expf(s11 - m1);
        float i0 = 1.f / (e00 + e01), i1 = 1.f / (e10 + e11);
        wsm[ib * 4 + 0] = e00 * i0; wsm[ib * 4 + 1] = e01 * i0;
        wsm[ib * 4 + 2] = e10 * i1; wsm[ib * 4 + 3] = e11 * i1;
    }
    __syncthreads();

    // 3) out = attn @ v, write global (128 rows x 64 cols = 1024 8-elem chunks)
#pragma unroll
    for (int gg = 0; gg < 4; gg++) {
        int chunk = gg * 256 + tid;
        int r = chunk >> 3;
        int dc = (chunk & 7) * 8;
        int ib = r >> 1, n = r & 1;
        float w0 = wsm[ib * 4 + n * 2 + 0];
        float w1 = wsm[ib * 4 + n * 2 + 1];
        short8 o;
#pragma unroll
        for (int dd = 0; dd < 8; dd++) {
            unsigned int vp = *(const unsigned int*)&T2[(128 + dc + dd) * T2_STRIDE + 2 * ib];
            o[dd] = (short)f2bf(w0 * lo_bf(vp) + w1 * hi_bf(vp));
        }
        *(short8*)&attn_out[(size_t)(blockM + r) * 1024 + h * 64 + dc] = o;
    }
}

// ---------- LayerNorm(2048) + residual ----------
__global__ __launch_bounds__(256) void ln_res_kernel(const unsigned short* __restrict__ proj,
                                                     const unsigned short* __restrict__ xres,
                                                     const float* __restrict__ gamma,
                                                     const float* __restrict__ beta,
                                                     float* __restrict__ out) {
    const int b = blockIdx.x;
    const int tid = threadIdx.x;
    const size_t base = (size_t)b * 2048;
    short8 p8 = ((const short8*)(proj + base))[tid];
    float pv[8];
#pragma unroll
    for (int e = 0; e < 8; e++) pv[e] = bf2f((unsigned short)p8[e]);
    float s = 0.f, ss = 0.f;
#pragma unroll
    for (int e = 0; e < 8; e++) { s += pv[e]; ss += pv[e] * pv[e]; }
#pragma unroll
    for (int off = 32; off > 0; off >>= 1) {
        s  += __shfl_xor(s, off);
        ss += __shfl_xor(ss, off);
    }
    __shared__ float red[8];
    const int wave = tid >> 6;
    if ((tid & 63) == 0) { red[wave] = s; red[4 + wave] = ss; }
    __syncthreads();
    s  = red[0] + red[1] + red[2] + red[3];
    ss = red[4] + red[5] + red[6] + red[7];
    const float mean = s * (1.0f / 2048.0f);
    const float var  = ss * (1.0f / 2048.0f) - mean * mean;
    const float rstd = rsqrtf(var + 1e-5f);

    const float4* g4 = (const float4*)gamma;
    const float4* b4 = (const float4*)beta;
    float4 g0 = g4[2 * tid], g1 = g4[2 * tid + 1];
    float4 be0 = b4[2 * tid], be1 = b4[2 * tid + 1];
    short8 r8 = ((const short8*)(xres + base))[tid];
    float4 o0, o1;
    o0.x = (pv[0] - mean) * rstd * g0.x + be0.x + bf2f((unsigned short)r8[0]);
    o0.y = (pv[1] - mean) * rstd * g0.y + be0.y + bf2f((unsigned short)r8[1]);
    o0.z = (pv[2] - mean) * rstd * g0.z + be0.z + bf2f((unsigned short)r8[2]);
    o0.w = (pv[3] - mean) * rstd * g0.w + be0.w + bf2f((unsigned short)r8[3]);
    o1.x = (pv[4] - mean) * rstd * g1.x + be1.x + bf2f((unsigned short)r8[4]);
    o1.y = (pv[5] - mean) * rstd * g1.y + be1.y + bf2f((unsigned short)r8[5]);
    o1.z = (pv[6] - mean) * rstd * g1.z + be1.z + bf2f((unsigned short)r8[6]);
    o1.w = (pv[7] - mean) * rstd * g1.w + be1.w + bf2f((unsigned short)r8[7]);
    float4* op = (float4*)(out + base);
    op[2 * tid] = o0;
    op[2 * tid + 1] = o1;
}

// ---------- launch ----------
extern "C" void kernel_launch(void* const* d_in, const int* in_sizes, int n_in,
                              void* d_out, int out_size, void* d_ws, size_t ws_size,
                              hipStream_t stream) {
    (void)in_sizes; (void)n_in; (void)out_size; (void)ws_size;
    const float* features1 = (const float*)d_in[0];
    const float* features2 = (const float*)d_in[1];
    const float* W1   = (const float*)d_in[2];
    const float* b1   = (const float*)d_in[3];
    const float* W2   = (const float*)d_in[4];
    const float* b2   = (const float*)d_in[5];
    const float* Wqkv = (const float*)d_in[6];
    const float* Wout = (const float*)d_in[7];
    const float* bout = (const float*)d_in[8];
    const float* gamma = (const float*)d_in[9];
    const float* beta  = (const float*)d_in[10];
    float* out = (float*)d_out;

    // B=8192, IMG=2048, Q=768, H=1024  (f1b/f2b slots retired; offsets kept)
    char* ws = (char*)d_ws;
    unsigned short* W1t   = (unsigned short*)(ws + 46137344);      // 4 MiB   [1024][2048]
    unsigned short* W2t   = (unsigned short*)(ws + 50331648);      // 1.5 MiB [1024][768]
    unsigned short* Wqkvt = (unsigned short*)(ws + 51904512);      // 6 MiB   [3072][1024]
    unsigned short* Woutt = (unsigned short*)(ws + 58195968);      // 2 MiB   [1024][1024]
    unsigned short* xb    = (unsigned short*)(ws + 60293120);      // 32 MiB  [16384][1024]
    unsigned short* attn  = (unsigned short*)(ws + 93847552);      // 32 MiB  [16384][1024]
    unsigned short* projb = (unsigned short*)(ws + 127401984);     // 32 MiB  [16384][1024] bf16

    // 1) weight transposes only (feature cvt fused into gemm_f12)
    prep_kernel<<<3456, 256, 0, stream>>>(W1, W1t, W2, W2t, Wqkv, Wqkvt, Wout, Woutt);
    // 2) f1/f2 modality GEMMs reading f32 features directly (fused cvt, early-issue A)
    gemm_f12<<<dim3(64, 8, 2), 256, 0, stream>>>(features1, W1t, b1, features2, W2t, b2, xb);
    // 3) fused qkv GEMM + attention (r1 exact)
    gemm_qkv_attn<<<2048, 256, 0, stream>>>(xb, Wqkvt, attn);
    // 4) proj = attn @ Wout + bout -> bf16
    gemm_proj<<<dim3(128, 8), 256, 0, stream>>>(attn, Woutt, bout, projb);
    // 5) LayerNorm + residual
    ln_res_kernel<<<8192, 256, 0, stream>>>(projb, xb, gamma, beta, out);
}

// Round 11
// 365.415 us; speedup vs baseline: 1.0215x; 1.0215x over previous
//
#include <hip/hip_runtime.h>
#include <hip/hip_bf16.h>
#include <cstdint>

// ---------- types ----------
typedef __attribute__((ext_vector_type(8))) short short8;     // 8 x bf16 raw
typedef __attribute__((ext_vector_type(4))) short short4v;    // 4 x bf16 raw
typedef __attribute__((ext_vector_type(4))) float floatx4;
typedef __attribute__((ext_vector_type(4))) unsigned short ushort4v;

// ---------- helpers ----------
__device__ __forceinline__ float bf2f(unsigned short u) {
    union { unsigned int u; float f; } v;
    v.u = ((unsigned int)u) << 16;
    return v.f;
}
__device__ __forceinline__ unsigned short f2bf(float f) {
    union { float f; unsigned int u; } v; v.f = f;
    unsigned int u = v.u;
    unsigned int r = (u + 0x7FFFu + ((u >> 16) & 1u)) >> 16;  // RNE
    return (unsigned short)r;
}
__device__ __forceinline__ float lo_bf(unsigned int u) {
    union { unsigned int u; float f; } v; v.u = u << 16; return v.f;
}
__device__ __forceinline__ float hi_bf(unsigned int u) {
    union { unsigned int u; float f; } v; v.u = u & 0xffff0000u; return v.f;
}
__device__ __forceinline__ void gld_lds16(const void* g, void* l) {
    __builtin_amdgcn_global_load_lds(
        (const __attribute__((address_space(1))) unsigned int*)g,
        (__attribute__((address_space(3))) unsigned int*)l,
        16, 0, 0);
}

// ---------- unified prep: feature cvt + all weight transposes, ONE dispatch ----------
__global__ __launch_bounds__(256) void prep_kernel(
    const float* __restrict__ f1, const float* __restrict__ f2,
    unsigned short* __restrict__ f1b, unsigned short* __restrict__ f2b,
    const float* __restrict__ W1, unsigned short* __restrict__ W1t,
    const float* __restrict__ W2, unsigned short* __restrict__ W2t,
    const float* __restrict__ Wqkv, unsigned short* __restrict__ Wqkvt,
    const float* __restrict__ Wout, unsigned short* __restrict__ Woutt) {
    __shared__ float tile[64][33];
    const int b = blockIdx.x;
    const int tid = threadIdx.x;

    if (b < 5632) {
        const float* in = (b < 4096) ? f1 : f2;
        unsigned short* outp = (b < 4096) ? f1b : f2b;
        int base = ((b < 4096) ? b : (b - 4096)) * 1024 + tid;
#pragma unroll
        for (int it = 0; it < 4; it++) {
            int i = base + it * 256;
            float4 v = ((const float4*)in)[i];
            ushort4v o;
            o.x = f2bf(v.x); o.y = f2bf(v.y); o.z = f2bf(v.z); o.w = f2bf(v.w);
            ((ushort4v*)outp)[i] = o;
        }
        return;
    }

    const float* in; unsigned short* outp; int K, N, t;
    if (b < 6656)      { in = W1;   outp = W1t;   K = 2048; N = 1024; t = b - 5632; }
    else if (b < 7040) { in = W2;   outp = W2t;   K = 768;  N = 1024; t = b - 6656; }
    else if (b < 8576) { in = Wqkv; outp = Wqkvt; K = 1024; N = 3072; t = b - 7040; }
    else               { in = Wout; outp = Woutt; K = 1024; N = 1024; t = b - 8576; }
    const int ntiles = N >> 5;
    const int n0 = (t % ntiles) * 32;
    const int k0 = (t / ntiles) * 64;
    const int tx = tid & 31, tg = tid >> 5;
#pragma unroll
    for (int i = 0; i < 8; i++)
        tile[tg * 8 + i][tx] = in[(size_t)(k0 + tg * 8 + i) * N + n0 + tx];
    __syncthreads();
    const int n = tid >> 3, kc = (tid & 7) * 8;
    short8 o;
#pragma unroll
    for (int j = 0; j < 8; j++) o[j] = (short)f2bf(tile[kc + j][n]);
    *(short8*)&outp[(size_t)(n0 + n) * K + k0 + kc] = o;
}

// ---------- bf16 GEMM core, BK=64 (r1-verified: swizzled LDS, 2-phase) ----------
template <bool OUT_BF16, bool HAS_BIAS>
__device__ __forceinline__ void gemm_core(const unsigned short* __restrict__ A,
                                          const unsigned short* __restrict__ Bt,
                                          void* __restrict__ Cv, const float* __restrict__ bias,
                                          int K, int ldc, int blockM, int blockN,
                                          unsigned short* As, unsigned short* Bs) {
    const int tid  = threadIdx.x;
    const int lane = tid & 63;
    const int wave = tid >> 6;
    const int wm = wave >> 1, wn = wave & 1;

    const int kx = (tid >> 3) & 3;
    const unsigned short* gA = A  + (size_t)(blockM + (tid >> 2)) * K + ((tid & 3) ^ kx) * 8;
    const unsigned short* gB = Bt + (size_t)(blockN + (tid >> 2)) * K + ((tid & 3) ^ kx) * 8;
    const size_t sK = (size_t)64 * K;
    unsigned short* lA = As + wave * 512;
    unsigned short* lB = Bs + wave * 512;

    floatx4 acc[4][4];
#pragma unroll
    for (int i = 0; i < 4; i++)
#pragma unroll
        for (int j = 0; j < 4; j++) acc[i][j] = (floatx4){0.f, 0.f, 0.f, 0.f};

    const int col  = lane & 15;
    const int quad = lane >> 4;
    const int qx = quad ^ ((col >> 1) & 3);
    const int aoff32 = (wm * 64 + col) * 32 + qx * 8;
    const int boff32 = (wn * 64 + col) * 32 + qx * 8;

    const int kIters = K >> 6;
    for (int kt = 0; kt < kIters; ++kt) {
        const size_t ko = (size_t)kt * 64;
        gld_lds16(gA + ko,           lA);
        gld_lds16(gA + sK + ko,      lA + 2048);
        gld_lds16(gA + 32 + ko,      lA + 4096);
        gld_lds16(gA + sK + 32 + ko, lA + 6144);
        gld_lds16(gB + ko,           lB);
        gld_lds16(gB + sK + ko,      lB + 2048);
        gld_lds16(gB + 32 + ko,      lB + 4096);
        gld_lds16(gB + sK + 32 + ko, lB + 6144);
        __syncthreads();

#pragma unroll
        for (int hh = 0; hh < 2; hh++) {
            short8 a[4];
#pragma unroll
            for (int i = 0; i < 4; i++) a[i] = *(const short8*)&As[hh * 4096 + aoff32 + i * 512];
#pragma unroll
            for (int j = 0; j < 4; j++) {
                short8 bj = *(const short8*)&Bs[hh * 4096 + boff32 + j * 512];
#pragma unroll
                for (int i = 0; i < 4; i++)
                    acc[i][j] = __builtin_amdgcn_mfma_f32_16x16x32_bf16(a[i], bj, acc[i][j], 0, 0, 0);
            }
        }
        __syncthreads();
    }

#pragma unroll
    for (int i = 0; i < 4; i++) {
#pragma unroll
        for (int j = 0; j < 4; j++) {
#pragma unroll
            for (int r = 0; r < 4; r++) {
                int row = blockM + wm * 64 + i * 16 + quad * 4 + r;
                int cn  = blockN + wn * 64 + j * 16 + col;
                float v = acc[i][j][r];
                if (HAS_BIAS) v += bias[cn];
                if (OUT_BF16) ((unsigned short*)Cv)[(size_t)row * ldc + cn] = f2bf(v);
                else          ((float*)Cv)[(size_t)row * ldc + cn] = v;
            }
        }
    }
}

// ---------- merged modality GEMMs ----------
// (256,4): LDS 32KB, VGPR 72 -> 4 blocks/CU; 1024-block grid = exactly one occupancy round.
__global__ __launch_bounds__(256, 4)
void gemm_f12(const unsigned short* __restrict__ f1b, const unsigned short* __restrict__ W1t,
              const float* __restrict__ b1,
              const unsigned short* __restrict__ f2b, const unsigned short* __restrict__ W2t,
              const float* __restrict__ b2, unsigned short* __restrict__ xb) {
    __shared__ alignas(16) unsigned short As[8192];
    __shared__ alignas(16) unsigned short Bs[8192];
    const int blockM = blockIdx.x * 128;   // M fastest: blocks sharing B-weights run consecutively;
    const int blockN = blockIdx.y * 128;   // blocks sharing A differ only in y => same XCD (x mod 8 fixed)
    if (blockIdx.z == 0)
        gemm_core<true, true>(f1b, W1t, (void*)xb, b1, 2048, 2048, blockM, blockN, As, Bs);
    else
        gemm_core<true, true>(f2b, W2t, (void*)(xb + 1024), b2, 768, 2048, blockM, blockN, As, Bs);
}

// ---------- out-proj GEMM ----------
__global__ __launch_bounds__(256, 4)
void gemm_proj(const unsigned short* __restrict__ attn, const unsigned short* __restrict__ Woutt,
               const float* __restrict__ bout, unsigned short* __restrict__ projb) {
    __shared__ alignas(16) unsigned short As[8192];
    __shared__ alignas(16) unsigned short Bs[8192];
    gemm_core<true, true>(attn, Woutt, (void*)projb, bout, 1024, 1024,
                          blockIdx.x * 128, blockIdx.y * 128, As, Bs);
}

// ---------- fused qkv GEMM + 2x2 attention (r1 exact; best verified 100.5 us) ----------
#define T2_STRIDE 132
__global__ __launch_bounds__(256, 3)
void gemm_qkv_attn(const unsigned short* __restrict__ A, const unsigned short* __restrict__ Bt,
                   unsigned short* __restrict__ attn_out) {
    __shared__ alignas(16) char smem[52224];
    unsigned short* As = (unsigned short*)smem;        // 8192 elems: 2 halves x [128][32]
    unsigned short* Bs = As + 8192;                    // 12288 elems: 2 halves x [192][32]
    unsigned short* T2 = (unsigned short*)smem;        // 192*132 elems, reuses staging
    float* wsm = (float*)(smem + 50688);               // 64*4 softmax weights

    const int tid  = threadIdx.x;
    const int lane = tid & 63;
    const int wave = tid >> 6;
    const int g = blockIdx.x;
    const int h = g >> 7;                     // head 0..15
    const int blockM = (g & 127) * 128;       // M-tile fastest => same-XCD A sharing
    const int wm = wave >> 1, wn = wave & 1;  // wave tile 64x96
    const int K = 1024;

    const int kx = (tid >> 3) & 3;            // staging-side chunk XOR (verified r1)
    const unsigned short* gA = A  + (size_t)(blockM + (tid >> 2)) * K + ((tid & 3) ^ kx) * 8;
    const unsigned short* gB = Bt + (size_t)(h * 64 + (tid >> 2)) * K + ((tid & 3) ^ kx) * 8;
    unsigned short* lA = As + wave * 512;
    unsigned short* lB = Bs + wave * 512;

    floatx4 acc[4][6];
#pragma unroll
    for (int i = 0; i < 4; i++)
#pragma unroll
        for (int j = 0; j < 6; j++) acc[i][j] = (floatx4){0.f, 0.f, 0.f, 0.f};

    const int col  = lane & 15;
    const int quad = lane >> 4;
    const int qx = quad ^ ((col >> 1) & 3);   // read-side swizzled chunk (verified r1)
    const int aoff32 = (wm * 64 + col) * 32 + qx * 8;
    const int boff32 = (wn * 96 + col) * 32 + qx * 8;

    for (int kt = 0; kt < 16; ++kt) {
        const size_t ko = (size_t)kt * 64;
        gld_lds16(gA + ko,               lA);          // A half0 rows 0..63
        gld_lds16(gA + 65536 + ko,       lA + 2048);   // A half0 rows 64..127
        gld_lds16(gA + 32 + ko,          lA + 4096);   // A half1 rows 0..63
        gld_lds16(gA + 65536 + 32 + ko,  lA + 6144);   // A half1 rows 64..127
        gld_lds16(gB + ko,               lB);          // q, half0
        gld_lds16(gB + 1048576 + ko,     lB + 2048);   // k, half0
        gld_lds16(gB + 2097152 + ko,     lB + 4096);   // v, half0
        gld_lds16(gB + 32 + ko,          lB + 6144);   // q, half1
        gld_lds16(gB + 1048576 + 32 + ko, lB + 8192);  // k, half1
        gld_lds16(gB + 2097152 + 32 + ko, lB + 10240); // v, half1
        __syncthreads();

#pragma unroll
        for (int hh = 0; hh < 2; hh++) {
            short8 a[4];
#pragma unroll
            for (int i = 0; i < 4; i++) a[i] = *(const short8*)&As[hh * 4096 + aoff32 + i * 512];
#pragma unroll
            for (int j = 0; j < 6; j++) {
                short8 bj = *(const short8*)&Bs[hh * 6144 + boff32 + j * 512];
#pragma unroll
                for (int i = 0; i < 4; i++)
                    acc[i][j] = __builtin_amdgcn_mfma_f32_16x16x32_bf16(a[i], bj, acc[i][j], 0, 0, 0);
            }
        }
        __syncthreads();
    }

    // 1) store tile transposed: T2[c][r], c = feature (q|k|v), r = M-row
#pragma unroll
    for (int i = 0; i < 4; i++) {
#pragma unroll
        for (int j = 0; j < 6; j++) {
            int c  = wn * 96 + j * 16 + col;
            int r0 = wm * 64 + i * 16 + quad * 4;
            short4v pk;
            pk.x = (short)f2bf(acc[i][j][0]);
            pk.y = (short)f2bf(acc[i][j][1]);
            pk.z = (short)f2bf(acc[i][j][2]);
            pk.w = (short)f2bf(acc[i][j][3]);
            *(short4v*)&T2[c * T2_STRIDE + r0] = pk;
        }
    }
    __syncthreads();

    // 2) scores + softmax: thread ib (<64) handles batch-row pair (2ib, 2ib+1)
    if (tid < 64) {
        const int ib = tid;
        float s00 = 0.f, s01 = 0.f, s10 = 0.f, s11 = 0.f;
#pragma unroll 8
        for (int d = 0; d < 64; d++) {
            unsigned int qp = *(const unsigned int*)&T2[d * T2_STRIDE + 2 * ib];
            unsigned int kp = *(const unsigned int*)&T2[(64 + d) * T2_STRIDE + 2 * ib];
            float q0 = lo_bf(qp), q1 = hi_bf(qp);
            float k0 = lo_bf(kp), k1 = hi_bf(kp);
            s00 += q0 * k0; s01 += q0 * k1;
            s10 += q1 * k0; s11 += q1 * k1;
        }
        const float sc = 0.125f;   // (1024/16)^-0.5
        s00 *= sc; s01 *= sc; s10 *= sc; s11 *= sc;
        float m0 = fmaxf(s00, s01), m1 = fmaxf(s10, s11);
        float e00 = __expf(s00 - m0), e01 = __expf(s01 - m0);
        float e10 = __expf(s10 - m1), e11 = __expf(s11 - m1);
        float i0 = 1.f / (e00 + e01), i1 = 1.f / (e10 + e11);
        wsm[ib * 4 + 0] = e00 * i0; wsm[ib * 4 + 1] = e01 * i0;
        wsm[ib * 4 + 2] = e10 * i1; wsm[ib * 4 + 3] = e11 * i1;
    }
    __syncthreads();

    // 3) out = attn @ v, write global (128 rows x 64 cols = 1024 8-elem chunks)
#pragma unroll
    for (int gg = 0; gg < 4; gg++) {
        int chunk = gg * 256 + tid;
        int r = chunk >> 3;
        int dc = (chunk & 7) * 8;
        int ib = r >> 1, n = r & 1;
        float w0 = wsm[ib * 4 + n * 2 + 0];
        float w1 = wsm[ib * 4 + n * 2 + 1];
        short8 o;
#pragma unroll
        for (int dd = 0; dd < 8; dd++) {
            unsigned int vp = *(const unsigned int*)&T2[(128 + dc + dd) * T2_STRIDE + 2 * ib];
            o[dd] = (short)f2bf(w0 * lo_bf(vp) + w1 * hi_bf(vp));
        }
        *(short8*)&attn_out[(size_t)(blockM + r) * 1024 + h * 64 + dc] = o;
    }
}

// ---------- LayerNorm(2048) + residual ----------
__global__ __launch_bounds__(256) void ln_res_kernel(const unsigned short* __restrict__ proj,
                                                     const unsigned short* __restrict__ xres,
                                                     const float* __restrict__ gamma,
                                                     const float* __restrict__ beta,
                                                     float* __restrict__ out) {
    const int b = blockIdx.x;
    const int tid = threadIdx.x;
    const size_t base = (size_t)b * 2048;
    short8 p8 = ((const short8*)(proj + base))[tid];
    float pv[8];
#pragma unroll
    for (int e = 0; e < 8; e++) pv[e] = bf2f((unsigned short)p8[e]);
    float s = 0.f, ss = 0.f;
#pragma unroll
    for (int e = 0; e < 8; e++) { s += pv[e]; ss += pv[e] * pv[e]; }
#pragma unroll
    for (int off = 32; off > 0; off >>= 1) {
        s  += __shfl_xor(s, off);
        ss += __shfl_xor(ss, off);
    }
    __shared__ float red[8];
    const int wave = tid >> 6;
    if ((tid & 63) == 0) { red[wave] = s; red[4 + wave] = ss; }
    __syncthreads();
    s  = red[0] + red[1] + red[2] + red[3];
    ss = red[4] + red[5] + red[6] + red[7];
    const float mean = s * (1.0f / 2048.0f);
    const float var  = ss * (1.0f / 2048.0f) - mean * mean;
    const float rstd = rsqrtf(var + 1e-5f);

    const float4* g4 = (const float4*)gamma;
    const float4* b4 = (const float4*)beta;
    float4 g0 = g4[2 * tid], g1 = g4[2 * tid + 1];
    float4 be0 = b4[2 * tid], be1 = b4[2 * tid + 1];
    short8 r8 = ((const short8*)(xres + base))[tid];
    float4 o0, o1;
    o0.x = (pv[0] - mean) * rstd * g0.x + be0.x + bf2f((unsigned short)r8[0]);
    o0.y = (pv[1] - mean) * rstd * g0.y + be0.y + bf2f((unsigned short)r8[1]);
    o0.z = (pv[2] - mean) * rstd * g0.z + be0.z + bf2f((unsigned short)r8[2]);
    o0.w = (pv[3] - mean) * rstd * g0.w + be0.w + bf2f((unsigned short)r8[3]);
    o1.x = (pv[4] - mean) * rstd * g1.x + be1.x + bf2f((unsigned short)r8[4]);
    o1.y = (pv[5] - mean) * rstd * g1.y + be1.y + bf2f((unsigned short)r8[5]);
    o1.z = (pv[6] - mean) * rstd * g1.z + be1.z + bf2f((unsigned short)r8[6]);
    o1.w = (pv[7] - mean) * rstd * g1.w + be1.w + bf2f((unsigned short)r8[7]);
    float4* op = (float4*)(out + base);
    op[2 * tid] = o0;
    op[2 * tid + 1] = o1;
}

// ---------- launch ----------
extern "C" void kernel_launch(void* const* d_in, const int* in_sizes, int n_in,
                              void* d_out, int out_size, void* d_ws, size_t ws_size,
                              hipStream_t stream) {
    (void)in_sizes; (void)n_in; (void)out_size; (void)ws_size;
    const float* features1 = (const float*)d_in[0];
    const float* features2 = (const float*)d_in[1];
    const float* W1   = (const float*)d_in[2];
    const float* b1   = (const float*)d_in[3];
    const float* W2   = (const float*)d_in[4];
    const float* b2   = (const float*)d_in[5];
    const float* Wqkv = (const float*)d_in[6];
    const float* Wout = (const float*)d_in[7];
    const float* bout = (const float*)d_in[8];
    const float* gamma = (const float*)d_in[9];
    const float* beta  = (const float*)d_in[10];
    float* out = (float*)d_out;

    // B=8192, IMG=2048, Q=768, H=1024
    char* ws = (char*)d_ws;
    unsigned short* f1b   = (unsigned short*)(ws);                 // 32 MiB
    unsigned short* f2b   = (unsigned short*)(ws + 33554432);      // 12 MiB
    unsigned short* W1t   = (unsigned short*)(ws + 46137344);      // 4 MiB   [1024][2048]
    unsigned short* W2t   = (unsigned short*)(ws + 50331648);      // 1.5 MiB [1024][768]
    unsigned short* Wqkvt = (unsigned short*)(ws + 51904512);      // 6 MiB   [3072][1024]
    unsigned short* Woutt = (unsigned short*)(ws + 58195968);      // 2 MiB   [1024][1024]
    unsigned short* xb    = (unsigned short*)(ws + 60293120);      // 32 MiB  [16384][1024]
    unsigned short* attn  = (unsigned short*)(ws + 93847552);      // 32 MiB  [16384][1024]
    unsigned short* projb = (unsigned short*)(ws + 127401984);     // 32 MiB  [16384][1024] bf16

    // 1) unified prep (feature cvt + weight transposes)
    prep_kernel<<<9088, 256, 0, stream>>>(features1, features2, f1b, f2b,
                                          W1, W1t, W2, W2t, Wqkv, Wqkvt, Wout, Woutt);
    // 2) f1/f2 modality GEMMs (4 blocks/CU -> exactly one occupancy round)
    gemm_f12<<<dim3(64, 8, 2), 256, 0, stream>>>(f1b, W1t, b1, f2b, W2t, b2, xb);
    // 3) fused qkv GEMM + attention (r1 exact)
    gemm_qkv_attn<<<2048, 256, 0, stream>>>(xb, Wqkvt, attn);
    // 4) proj = attn @ Wout + bout -> bf16 (4 blocks/CU -> exactly one round)
    gemm_proj<<<dim3(128, 8), 256, 0, stream>>>(attn, Woutt, bout, projb);
    // 5) LayerNorm + residual
    ln_res_kernel<<<8192, 256, 0, stream>>>(projb, xb, gamma, beta, out);
}